// Round 4
// baseline (936.155 us; speedup 1.0000x reference)
//
#include <hip/hip_runtime.h>

// RoutingCapsule: B=32, N_in=2048, N_out=64, D_out=32, D_in=16
// R7: fused_ts v3. R6's fused kernel was barrier-duty-cycle-bound:
// HBM only in flight during phase1 (~30% duty -> ~2 TB/s). Fixes:
//   - register prefetch: phase1 consumes pa[4] (preloaded W frags) and
//     immediately re-issues next-i loads into pa -> loads in flight
//     across the softmax barriers; phase3 re-reads current tile from L2
//   - wave-parallel softmax: 16 waves x 2 batch-cols, 6-step shfl_xor
//     butterflies; 3 barriers/i (was 5 + two serial 32-iter reductions)
//   - ct padded [64][33]: all LDS phases <=2-way bank aliasing (free)
// passA / convert / reduce / squash unchanged from R6 (clean A/B).

#define B_   32
#define NI   2048
#define NO   64
#define DO_  32
#define DI   16
#define IC   16
#define WSTRIDE ((size_t)NO * DO_ * DI)

typedef __bf16 bf16x8 __attribute__((ext_vector_type(8)));
typedef float  f32x16 __attribute__((ext_vector_type(16)));
union U16B { uint4 u; bf16x8 v; };

// ---------------- x -> xT bf16 in exact B-fragment order ----------------
__global__ __launch_bounds__(256) void convert_xT_kernel(const float* __restrict__ x,
                                                         __bf16* __restrict__ xT)
{
    const int idx = blockIdx.x * 256 + threadIdx.x;   // 131072 = 2048*2*32
    const int m = idx & 31;
    const int h = (idx >> 5) & 1;
    const int i = idx >> 6;
    const float4 f0 = *(const float4*)(x + ((size_t)m * NI + i) * DI + 8 * h);
    const float4 f1 = *(const float4*)(x + ((size_t)m * NI + i) * DI + 8 * h + 4);
    __bf16 o[8] = {(__bf16)f0.x, (__bf16)f0.y, (__bf16)f0.z, (__bf16)f0.w,
                   (__bf16)f1.x, (__bf16)f1.y, (__bf16)f1.z, (__bf16)f1.w};
    *(uint4*)(xT + (size_t)idx * 8) = *(uint4*)o;
}

// ---------------- pass A: convert W + s0 partials (R3 form) ----------------
__global__ __launch_bounds__(256) void passA_kernel(const float* __restrict__ W,
                                                    const __bf16* __restrict__ xT,
                                                    __bf16* __restrict__ Wb,
                                                    float* __restrict__ part)
{
    __shared__ float lds[4][1024];
    const int tid = threadIdx.x, lane = tid & 63, w = tid >> 6;
    const int j  = blockIdx.x & 63;
    const int ch = blockIdx.x >> 6;
    const int i0 = ch * 64 + w * IC;
    const int m  = lane & 31, h = lane >> 5;

    const size_t toff = (((size_t)i0 * NO + j) * DO_ + m) * DI + 8 * h;
    const float*  Wp  = W  + toff;
    __bf16*       Wbp = Wb + toff;
    const __bf16* xp  = xT + (size_t)i0 * 512 + lane * 8;

    f32x16 acc;
    #pragma unroll
    for (int r = 0; r < 16; ++r) acc[r] = 0.0f;

    #pragma unroll 4
    for (int ii = 0; ii < IC; ++ii) {
        const float4 w0 = ((const float4*)Wp)[0];
        const float4 w1 = ((const float4*)Wp)[1];
        U16B a;
        a.v[0] = (__bf16)w0.x; a.v[1] = (__bf16)w0.y; a.v[2] = (__bf16)w0.z; a.v[3] = (__bf16)w0.w;
        a.v[4] = (__bf16)w1.x; a.v[5] = (__bf16)w1.y; a.v[6] = (__bf16)w1.z; a.v[7] = (__bf16)w1.w;
        *(uint4*)Wbp = a.u;
        U16B b; b.u = *(const uint4*)xp;
        acc = __builtin_amdgcn_mfma_f32_32x32x16_bf16(a.v, b.v, acc, 0, 0, 0);
        Wp += WSTRIDE; Wbp += WSTRIDE; xp += 512;
    }

    #pragma unroll
    for (int r = 0; r < 16; ++r) {
        const int row = (r & 3) + 8 * (r >> 2) + 4 * h;
        lds[w][row * 32 + m] = acc[r];
    }
    __syncthreads();
    float* pb = part + ((size_t)ch * NO + j) * 1024;
    #pragma unroll
    for (int q = 0; q < 4; ++q) {
        const int idx = tid + 256 * q;
        pb[idx] = lds[0][idx] + lds[1][idx] + lds[2][idx] + lds[3][idx];
    }
}

// ---------------- fused t + softmax + s: one Wb sweep per iteration ------
// 1024 threads = 16 waves; wave w owns j = 4w..4w+3; block owns i = 8*bid..+7.
// vB layout: vB[((j*32)+b)*32 + d]  (batch-major, d contiguous)
__global__ __launch_bounds__(1024, 4) void fused_ts_kernel(const __bf16* __restrict__ Wb,
                                                           const __bf16* __restrict__ xT,
                                                           const float* __restrict__ vB,
                                                           float* __restrict__ part)
{
    __shared__ float ct[64][33];       // logits -> normalized c (pad: 2-way max)

    const int tid = threadIdx.x, lane = tid & 63, w = tid >> 6;  // w in [0,16)
    const int m = lane & 31, h = lane >> 5;
    const int i0 = blockIdx.x * 8;
    const int j0 = w * 4;

    f32x16 acc[4];
    #pragma unroll
    for (int jj = 0; jj < 4; ++jj) {
        #pragma unroll
        for (int r = 0; r < 16; ++r) acc[jj][r] = 0.0f;
    }
    f32x16 z;
    #pragma unroll
    for (int r = 0; r < 16; ++r) z[r] = 0.0f;

    // Wrow: this wave's fragment base for row i (advances by WSTRIDE per i)
    const __bf16* Wrow = Wb + (((size_t)i0 * NO + j0) * DO_ + m) * DI + 8 * h;

    // prologue: prefetch i0's W fragments into registers
    U16B pa[4];
    #pragma unroll
    for (int jj = 0; jj < 4; ++jj)
        pa[jj].u = *(const uint4*)(Wrow + (size_t)jj * 512);

    for (int ii = 0; ii < 8; ++ii) {
        const int i = i0 + ii;
        U16B xf; xf.u = *(const uint4*)(xT + (size_t)i * 512 + lane * 8);

        // ---- phase 1: u = W.x from prefetched regs; t[j,b] -> LDS;
        //      re-issue pa <- next i's fragments (in flight across barriers)
        #pragma unroll
        for (int jj = 0; jj < 4; ++jj) {
            f32x16 u = __builtin_amdgcn_mfma_f32_32x32x16_bf16(pa[jj].v, xf.v, z, 0, 0, 0);
            if (ii < 7)
                pa[jj].u = *(const uint4*)(Wrow + WSTRIDE + (size_t)jj * 512);
            const float* vpb = vB + (((size_t)(j0 + jj) * B_) + m) * DO_ + 4 * h;
            float p0 = 0.f, p1 = 0.f, p2 = 0.f, p3 = 0.f;
            #pragma unroll
            for (int q = 0; q < 4; ++q) {
                const float4 vv = *(const float4*)(vpb + 8 * q);
                p0 = fmaf(u[4 * q + 0], vv.x, p0);
                p1 = fmaf(u[4 * q + 1], vv.y, p1);
                p2 = fmaf(u[4 * q + 2], vv.z, p2);
                p3 = fmaf(u[4 * q + 3], vv.w, p3);
            }
            float tp = (p0 + p1) + (p2 + p3);
            tp += __shfl_xor(tp, 32);
            if (h == 0) ct[j0 + jj][m] = tp;
        }
        __syncthreads();

        // ---- phase 2: wave-parallel softmax; wave w owns b = 2w, 2w+1 ----
        #pragma unroll
        for (int bb = 0; bb < 2; ++bb) {
            const int bc = 2 * w + bb;
            const float tv = ct[lane][bc];
            float mx = tv;
            #pragma unroll
            for (int dd = 1; dd < 64; dd <<= 1) mx = fmaxf(mx, __shfl_xor(mx, dd));
            const float e = __expf(tv - mx);
            float ssum = e;
            #pragma unroll
            for (int dd = 1; dd < 64; dd <<= 1) ssum += __shfl_xor(ssum, dd);
            ct[lane][bc] = e * (1.0f / ssum);     // normalized c
        }
        __syncthreads();

        // ---- phase 3: re-read current tile from L2; acc += c*u ----
        #pragma unroll
        for (int jj = 0; jj < 4; ++jj) {
            U16B a2; a2.u = *(const uint4*)(Wrow + (size_t)jj * 512);
            f32x16 u = __builtin_amdgcn_mfma_f32_32x32x16_bf16(a2.v, xf.v, z, 0, 0, 0);
            const float c = ct[j0 + jj][m];
            #pragma unroll
            for (int r = 0; r < 16; ++r) acc[jj][r] = fmaf(c, u[r], acc[jj][r]);
        }
        Wrow += WSTRIDE;
        __syncthreads();   // protect ct before next i's phase1 writes
    }

    // ---- write s-partials: part[ch=blockIdx][j][d][b] ----
    float* pb = part + ((size_t)blockIdx.x * NO + j0) * 1024;
    #pragma unroll
    for (int jj = 0; jj < 4; ++jj) {
        #pragma unroll
        for (int r = 0; r < 16; ++r) {
            const int row = (r & 3) + 8 * (r >> 2) + 4 * h;
            pb[jj * 1024 + row * 32 + m] = acc[jj][r];
        }
    }
}

// ---------------- part 256ch -> 4ch reduce ----------------
__global__ __launch_bounds__(256) void reduce_kernel(const float* __restrict__ partF,
                                                     float* __restrict__ partR)
{
    const int j  = blockIdx.x & 63;
    const int cg = blockIdx.x >> 6;          // 0..3
    const int tid = threadIdx.x;
    #pragma unroll
    for (int q = 0; q < 4; ++q) {
        const int idx = tid + 256 * q;
        const float* p = partF + (((size_t)cg * 64) * NO + j) * 1024 + idx;
        float a = 0.f;
        #pragma unroll 16
        for (int k = 0; k < 64; ++k) a += p[(size_t)k * NO * 1024];
        partR[((size_t)cg * NO + j) * 1024 + idx] = a;
    }
}

// ---------------- squash (+ chunk reduction), standalone ----------------
// Writes v in [j][d][b] (out) and optionally batch-major [j][b][d] (vBout).
__global__ __launch_bounds__(256) void squash_kernel(const float* __restrict__ part,
                                                     const float* __restrict__ bias,
                                                     const float* __restrict__ v0T,
                                                     float* __restrict__ out,
                                                     float* __restrict__ vBout,
                                                     int mode, float prescale, int nch)
{
    __shared__ float red[8][32];
    __shared__ float scl[32];
    const int j = blockIdx.x;
    const int tid = threadIdx.x;
    const int b = tid & 31;
    const int g = tid >> 5;
    const int d0 = g * 4;

    float sv[4];
    #pragma unroll
    for (int q = 0; q < 4; ++q) {
        const float* p = part + (size_t)j * 1024 + (d0 + q) * 32 + b;
        float a = 0.f;
        #pragma unroll 8
        for (int ch = 0; ch < nch; ++ch) a += p[(size_t)ch * NO * 1024];
        sv[q] = a * prescale + bias[j * DO_ + d0 + q];
    }

    float p2s = 0.f;
    #pragma unroll
    for (int q = 0; q < 4; ++q) p2s = fmaf(sv[q], sv[q], p2s);
    red[g][b] = p2s;
    __syncthreads();
    if (tid < 32) {
        float n2 = 0.f;
        #pragma unroll
        for (int gg = 0; gg < 8; ++gg) n2 += red[gg][tid];
        scl[tid] = n2 / ((1.0f + n2) * sqrtf(n2 + 1e-7f));
    }
    __syncthreads();
    const float sc = scl[b];
    #pragma unroll
    for (int q = 0; q < 4; ++q) {
        const int d = d0 + q;
        float vq = sv[q] * sc;
        if (mode == 1) vq += v0T[((size_t)j * DO_ + d) * B_ + b];
        if (mode == 2) out[((size_t)b * NO + j) * DO_ + d] = vq;
        else           out[((size_t)j * DO_ + d) * B_ + b] = vq;
        if (vBout)     vBout[((size_t)j * B_ + b) * DO_ + d] = vq;
    }
}

extern "C" void kernel_launch(void* const* d_in, const int* in_sizes, int n_in,
                              void* d_out, int out_size, void* d_ws, size_t ws_size,
                              hipStream_t stream)
{
    const float* x    = (const float*)d_in[0];
    const float* W    = (const float*)d_in[1];
    const float* bias = (const float*)d_in[2];
    float* out = (float*)d_out;

    char* ws = (char*)d_ws;
    __bf16* Wb    = (__bf16*)ws;                               // 128 MB
    __bf16* xT    = (__bf16*)(ws + (size_t)134217728);         // 2 MB
    float*  partP = (float*) (ws + (size_t)136314880);         // 8 MB   (passA, 32 ch)
    float*  partF = (float*) (ws + (size_t)144703488);         // 64 MB  (fused, 256 ch)
    float*  partR = (float*) (ws + (size_t)211812352);         // 1 MB   (reduced, 4 ch)
    float*  v0T   = (float*) (ws + (size_t)212860928);         // 256 KB [j][d][b]
    float*  vsT   = (float*) (ws + (size_t)213123072);         // 256 KB [j][d][b]
    float*  vB0   = (float*) (ws + (size_t)213385216);         // 256 KB [j][b][d]
    float*  vB1   = (float*) (ws + (size_t)213647360);         // 256 KB [j][b][d]

    const dim3 tW(256), tF(1024);
    const dim3 gX(512), gP(2048), gF(256), gR(256), gSq(NO);

    convert_xT_kernel<<<gX, tW, 0, stream>>>(x, xT);

    // sweep 1: W -> Wb + s0 partials; squash0 -> v0 (both layouts)
    passA_kernel<<<gP, tW, 0, stream>>>(W, xT, Wb, partP);
    squash_kernel<<<gSq, tW, 0, stream>>>(partP, bias, nullptr, v0T, vB0,
                                          0, 1.0f / 64.0f, 32);

    // iteration 1: fused t/softmax/s sweep; vsT = v0 + v1
    fused_ts_kernel<<<gF, tF, 0, stream>>>(Wb, xT, vB0, partF);
    reduce_kernel<<<gR, tW, 0, stream>>>(partF, partR);
    squash_kernel<<<gSq, tW, 0, stream>>>(partR, bias, v0T, vsT, vB1,
                                          1, 1.0f, 4);

    // iteration 2: fused sweep with v0+v1; final v -> out
    fused_ts_kernel<<<gF, tF, 0, stream>>>(Wb, xT, vB1, partF);
    reduce_kernel<<<gR, tW, 0, stream>>>(partF, partR);
    squash_kernel<<<gSq, tW, 0, stream>>>(partR, bias, nullptr, out, nullptr,
                                          2, 1.0f, 4);
}

// Round 6
// 521.448 us; speedup vs baseline: 1.7953x; 1.7953x over previous
//
#include <hip/hip_runtime.h>

// RoutingCapsule: B=32, N_in=2048, N_out=64, D_out=32, D_in=16
// R9: back to the proven R3 5-sweep structure (520us), with the sweeps'
// actual limiter fixed: they were memory-LATENCY-bound (1 dependent
// 16-32B load per wave-iteration -> ~1.5-2.5 TB/s). Each big sweep now
// batches 4 independent iterations' loads back-to-back (4KB in flight
// per wave, 4x MLP) under "#pragma unroll 1" group loops so the compiler
// cannot full-unroll into R7-style register pressure (R7: allocator
// flipped to 64 VGPR + 640MB scratch). Arithmetic is bit-identical to R3.
//   convert_xT: x fp32 -> xT bf16 in B-fragment order   (2 MB)
//   passA:      stream W fp32 -> Wb bf16 + s0 partials  (batched G=4)
//   t-pass x2:  logits t[i][j][b]                       (batched G=4)
//   softmax x2: over j, in place
//   s-pass x2:  s partials = sum_i c*u_hat              (batched G=4)
//   squash x3:  reduce partials + squash

#define B_   32
#define NI   2048
#define NO   64
#define DO_  32
#define DI   16
#define IC   16
#define WSTRIDE ((size_t)NO * DO_ * DI)

typedef __bf16 bf16x8 __attribute__((ext_vector_type(8)));
typedef float  f32x16 __attribute__((ext_vector_type(16)));
union U16B { uint4 u; bf16x8 v; };

// ---------------- x -> xT bf16 in exact B-fragment order ----------------
// xT[((i*2+h)*32+m)*8 + e] = x[m][i][8h+e]
__global__ __launch_bounds__(256) void convert_xT_kernel(const float* __restrict__ x,
                                                         __bf16* __restrict__ xT)
{
    const int idx = blockIdx.x * 256 + threadIdx.x;   // 131072 = 2048*2*32
    const int m = idx & 31;
    const int h = (idx >> 5) & 1;
    const int i = idx >> 6;
    const float4 f0 = *(const float4*)(x + ((size_t)m * NI + i) * DI + 8 * h);
    const float4 f1 = *(const float4*)(x + ((size_t)m * NI + i) * DI + 8 * h + 4);
    __bf16 o[8] = {(__bf16)f0.x, (__bf16)f0.y, (__bf16)f0.z, (__bf16)f0.w,
                   (__bf16)f1.x, (__bf16)f1.y, (__bf16)f1.z, (__bf16)f1.w};
    *(uint4*)(xT + (size_t)idx * 8) = *(uint4*)o;
}

// ---------------- pass A: convert W + s0 partials (G=4 batched) ----------
__global__ __launch_bounds__(256) void passA_kernel(const float* __restrict__ W,
                                                    const __bf16* __restrict__ xT,
                                                    __bf16* __restrict__ Wb,
                                                    float* __restrict__ part)
{
    __shared__ float lds[4][1024];
    const int tid = threadIdx.x, lane = tid & 63, w = tid >> 6;
    const int j  = blockIdx.x & 63;
    const int ch = blockIdx.x >> 6;
    const int i0 = ch * 64 + w * IC;
    const int m  = lane & 31, h = lane >> 5;

    const size_t toff = (((size_t)i0 * NO + j) * DO_ + m) * DI + 8 * h;
    const float*  Wp  = W  + toff;
    __bf16*       Wbp = Wb + toff;
    const __bf16* xp  = xT + (size_t)i0 * 512 + lane * 8;

    f32x16 acc;
    #pragma unroll
    for (int r = 0; r < 16; ++r) acc[r] = 0.0f;

    #pragma unroll 1
    for (int g = 0; g < 4; ++g) {
        // batched load phase: 8 x 16B W + 4 x 16B xT issued back-to-back
        float4 wv0[4], wv1[4];
        uint4  xv[4];
        #pragma unroll
        for (int k = 0; k < 4; ++k) {
            const float4* wk = (const float4*)(Wp + (size_t)k * WSTRIDE);
            wv0[k] = wk[0];
            wv1[k] = wk[1];
        }
        #pragma unroll
        for (int k = 0; k < 4; ++k)
            xv[k] = *(const uint4*)(xp + (size_t)k * 512);

        // compute phase
        #pragma unroll
        for (int k = 0; k < 4; ++k) {
            U16B a;
            a.v[0] = (__bf16)wv0[k].x; a.v[1] = (__bf16)wv0[k].y;
            a.v[2] = (__bf16)wv0[k].z; a.v[3] = (__bf16)wv0[k].w;
            a.v[4] = (__bf16)wv1[k].x; a.v[5] = (__bf16)wv1[k].y;
            a.v[6] = (__bf16)wv1[k].z; a.v[7] = (__bf16)wv1[k].w;
            *(uint4*)(Wbp + (size_t)k * WSTRIDE) = a.u;
            U16B b; b.u = xv[k];
            acc = __builtin_amdgcn_mfma_f32_32x32x16_bf16(a.v, b.v, acc, 0, 0, 0);
        }
        Wp  += 4 * WSTRIDE;
        Wbp += 4 * WSTRIDE;
        xp  += 4 * 512;
    }

    #pragma unroll
    for (int r = 0; r < 16; ++r) {
        const int row = (r & 3) + 8 * (r >> 2) + 4 * h;
        lds[w][row * 32 + m] = acc[r];
    }
    __syncthreads();
    float* pb = part + ((size_t)ch * NO + j) * 1024;
    #pragma unroll
    for (int q = 0; q < 4; ++q) {
        const int idx = tid + 256 * q;
        pb[idx] = lds[0][idx] + lds[1][idx] + lds[2][idx] + lds[3][idx];
    }
}

// ---------------- t-pass (G=4 batched) ----------------
__global__ __launch_bounds__(256) void t_kernel(const __bf16* __restrict__ Wb,
                                                const __bf16* __restrict__ xT,
                                                const float* __restrict__ vT,
                                                float* __restrict__ t)
{
    const int tid = threadIdx.x, lane = tid & 63;
    const int wid = blockIdx.x * 4 + (tid >> 6);
    const int j   = wid & 63;
    const int i0  = (wid >> 6) * IC;
    const int m   = lane & 31, h = lane >> 5;

    const __bf16* Wp = Wb + (((size_t)i0 * NO + j) * DO_ + m) * DI + 8 * h;
    const __bf16* xp = xT + (size_t)i0 * 512 + lane * 8;

    float vr[16];
    #pragma unroll
    for (int r = 0; r < 16; ++r) {
        const int row = (r & 3) + 8 * (r >> 2) + 4 * h;
        vr[r] = vT[((size_t)j * DO_ + row) * B_ + m];
    }

    f32x16 z;
    #pragma unroll
    for (int r = 0; r < 16; ++r) z[r] = 0.0f;

    #pragma unroll 1
    for (int g = 0; g < 4; ++g) {
        uint4 av[4], xv[4];
        #pragma unroll
        for (int k = 0; k < 4; ++k)
            av[k] = *(const uint4*)(Wp + (size_t)k * WSTRIDE);
        #pragma unroll
        for (int k = 0; k < 4; ++k)
            xv[k] = *(const uint4*)(xp + (size_t)k * 512);

        #pragma unroll
        for (int k = 0; k < 4; ++k) {
            U16B a; a.u = av[k];
            U16B b; b.u = xv[k];
            f32x16 u = __builtin_amdgcn_mfma_f32_32x32x16_bf16(a.v, b.v, z, 0, 0, 0);

            float p0 = 0.f, p1 = 0.f, p2 = 0.f, p3 = 0.f;
            #pragma unroll
            for (int r = 0; r < 16; r += 4) {
                p0 = fmaf(u[r + 0], vr[r + 0], p0);
                p1 = fmaf(u[r + 1], vr[r + 1], p1);
                p2 = fmaf(u[r + 2], vr[r + 2], p2);
                p3 = fmaf(u[r + 3], vr[r + 3], p3);
            }
            float tp = (p0 + p1) + (p2 + p3);
            tp += __shfl_xor(tp, 32);
            if (h == 0) t[(size_t)(i0 + 4 * g + k) * (NO * B_) + j * B_ + m] = tp;
        }
        Wp += 4 * WSTRIDE;
        xp += 4 * 512;
    }
}

// ---------------- s-pass (G=4 batched) ----------------
__global__ __launch_bounds__(256) void s_kernel(const __bf16* __restrict__ Wb,
                                                const __bf16* __restrict__ xT,
                                                const float* __restrict__ c,
                                                float* __restrict__ part)
{
    __shared__ float lds[4][1024];
    const int tid = threadIdx.x, lane = tid & 63, w = tid >> 6;
    const int j  = blockIdx.x & 63;
    const int ch = blockIdx.x >> 6;
    const int i0 = ch * 64 + w * IC;
    const int m  = lane & 31, h = lane >> 5;

    const __bf16* Wp = Wb + (((size_t)i0 * NO + j) * DO_ + m) * DI + 8 * h;
    const __bf16* xp = xT + (size_t)i0 * 512 + lane * 8;
    const float*  cp = c  + (size_t)i0 * (NO * B_) + j * B_ + m;

    f32x16 acc, z;
    #pragma unroll
    for (int r = 0; r < 16; ++r) { acc[r] = 0.0f; z[r] = 0.0f; }

    #pragma unroll 1
    for (int g = 0; g < 4; ++g) {
        uint4 av[4], xv[4];
        float cv[4];
        #pragma unroll
        for (int k = 0; k < 4; ++k)
            av[k] = *(const uint4*)(Wp + (size_t)k * WSTRIDE);
        #pragma unroll
        for (int k = 0; k < 4; ++k)
            xv[k] = *(const uint4*)(xp + (size_t)k * 512);
        #pragma unroll
        for (int k = 0; k < 4; ++k)
            cv[k] = cp[(size_t)k * (NO * B_)];

        #pragma unroll
        for (int k = 0; k < 4; ++k) {
            U16B a; a.u = av[k];
            U16B b; b.u = xv[k];
            f32x16 u = __builtin_amdgcn_mfma_f32_32x32x16_bf16(a.v, b.v, z, 0, 0, 0);
            #pragma unroll
            for (int r = 0; r < 16; ++r) acc[r] = fmaf(cv[k], u[r], acc[r]);
        }
        Wp += 4 * WSTRIDE;
        xp += 4 * 512;
        cp += 4 * (NO * B_);
    }

    #pragma unroll
    for (int r = 0; r < 16; ++r) {
        const int row = (r & 3) + 8 * (r >> 2) + 4 * h;
        lds[w][row * 32 + m] = acc[r];
    }
    __syncthreads();
    float* pb = part + ((size_t)ch * NO + j) * 1024;
    #pragma unroll
    for (int q = 0; q < 4; ++q) {
        const int idx = tid + 256 * q;
        pb[idx] = lds[0][idx] + lds[1][idx] + lds[2][idx] + lds[3][idx];
    }
}

// ---------------- softmax over j per (i,b), in place ----------------
__global__ __launch_bounds__(256) void softmax_kernel(float* __restrict__ t)
{
    __shared__ float red[8][32];
    __shared__ float row_m[32];
    __shared__ float row_s[32];
    const int i = blockIdx.x;
    const int tid = threadIdx.x;
    const int b = tid & 31;
    const int g = tid >> 5;
    float* base = t + (size_t)i * (NO * B_);

    float tv[8];
    #pragma unroll
    for (int k = 0; k < 8; ++k) tv[k] = base[(g * 8 + k) * B_ + b];

    float m8 = tv[0];
    #pragma unroll
    for (int k = 1; k < 8; ++k) m8 = fmaxf(m8, tv[k]);
    red[g][b] = m8;
    __syncthreads();
    if (tid < 32) {
        float mm = red[0][tid];
        #pragma unroll
        for (int gg = 1; gg < 8; ++gg) mm = fmaxf(mm, red[gg][tid]);
        row_m[tid] = mm;
    }
    __syncthreads();
    const float mm = row_m[b];
    float e[8]; float ps = 0.f;
    #pragma unroll
    for (int k = 0; k < 8; ++k) { e[k] = __expf(tv[k] - mm); ps += e[k]; }
    __syncthreads();
    red[g][b] = ps;
    __syncthreads();
    if (tid < 32) {
        float ss = 0.f;
        #pragma unroll
        for (int gg = 0; gg < 8; ++gg) ss += red[gg][tid];
        row_s[tid] = 1.0f / ss;
    }
    __syncthreads();
    const float inv = row_s[b];
    #pragma unroll
    for (int k = 0; k < 8; ++k) base[(g * 8 + k) * B_ + b] = e[k] * inv;
}

// ---------------- squash (+ chunk reduction) ----------------
__global__ __launch_bounds__(256) void squash_kernel(const float* __restrict__ part,
                                                     const float* __restrict__ bias,
                                                     const float* __restrict__ v0T,
                                                     float* __restrict__ out,
                                                     int mode, float prescale)
{
    __shared__ float red[8][32];
    __shared__ float scl[32];
    const int j = blockIdx.x;
    const int tid = threadIdx.x;
    const int b = tid & 31;
    const int g = tid >> 5;
    const int d0 = g * 4;

    float sv[4];
    #pragma unroll
    for (int q = 0; q < 4; ++q) {
        const float* p = part + (size_t)j * 1024 + (d0 + q) * 32 + b;
        float a = 0.f;
        #pragma unroll
        for (int ch = 0; ch < 32; ++ch) a += p[(size_t)ch * NO * 1024];
        sv[q] = a * prescale + bias[j * DO_ + d0 + q];
    }

    float p2s = 0.f;
    #pragma unroll
    for (int q = 0; q < 4; ++q) p2s = fmaf(sv[q], sv[q], p2s);
    red[g][b] = p2s;
    __syncthreads();
    if (tid < 32) {
        float n2 = 0.f;
        #pragma unroll
        for (int gg = 0; gg < 8; ++gg) n2 += red[gg][tid];
        scl[tid] = n2 / ((1.0f + n2) * sqrtf(n2 + 1e-7f));
    }
    __syncthreads();
    const float sc = scl[b];
    #pragma unroll
    for (int q = 0; q < 4; ++q) {
        const int d = d0 + q;
        const float vq = sv[q] * sc;
        if (mode == 0)      out[((size_t)j * DO_ + d) * B_ + b] = vq;
        else if (mode == 1) out[((size_t)j * DO_ + d) * B_ + b] =
                                v0T[((size_t)j * DO_ + d) * B_ + b] + vq;
        else                out[((size_t)b * NO + j) * DO_ + d] = vq;
    }
}

extern "C" void kernel_launch(void* const* d_in, const int* in_sizes, int n_in,
                              void* d_out, int out_size, void* d_ws, size_t ws_size,
                              hipStream_t stream)
{
    const float* x    = (const float*)d_in[0];
    const float* W    = (const float*)d_in[1];
    const float* bias = (const float*)d_in[2];
    float* out = (float*)d_out;

    char* ws = (char*)d_ws;
    __bf16* Wb   = (__bf16*)ws;                                   // 128 MB
    __bf16* xT   = (__bf16*)(ws + (size_t)134217728);             // 2 MB
    float*  t_buf= (float*) (ws + (size_t)134217728 + 2097152);   // 16 MB
    float*  part = (float*) (ws + (size_t)134217728 + 2097152 + 16777216); // 8 MB
    float*  v0T  = (float*) (ws + (size_t)134217728 + 2097152 + 16777216 + 8388608);
    float*  vsT  = v0T + (size_t)NO * DO_ * B_;

    const dim3 tW(256);
    const dim3 gX(512), gP(2048), gSm(NI), gSq(NO);

    convert_xT_kernel<<<gX, tW, 0, stream>>>(x, xT);

    passA_kernel<<<gP, tW, 0, stream>>>(W, xT, Wb, part);
    squash_kernel<<<gSq, tW, 0, stream>>>(part, bias, nullptr, v0T, 0, 1.0f / 64.0f);

    t_kernel<<<gP, tW, 0, stream>>>(Wb, xT, v0T, t_buf);
    softmax_kernel<<<gSm, tW, 0, stream>>>(t_buf);
    s_kernel<<<gP, tW, 0, stream>>>(Wb, xT, t_buf, part);
    squash_kernel<<<gSq, tW, 0, stream>>>(part, bias, v0T, vsT, 1, 1.0f);

    t_kernel<<<gP, tW, 0, stream>>>(Wb, xT, vsT, t_buf);
    softmax_kernel<<<gSm, tW, 0, stream>>>(t_buf);
    s_kernel<<<gP, tW, 0, stream>>>(Wb, xT, t_buf, part);
    squash_kernel<<<gSq, tW, 0, stream>>>(part, bias, nullptr, out, 2, 1.0f);
}